// Round 3
// baseline (1054.547 us; speedup 1.0000x reference)
//
#include <hip/hip_runtime.h>
#include <hip/hip_bf16.h>

#define HID 128

__device__ __forceinline__ float b2f(unsigned short u) {
    union { unsigned i; float f; } v; v.i = ((unsigned)u) << 16; return v.f;
}
__device__ __forceinline__ unsigned short f2b(float f) {
    unsigned u = __float_as_uint(f);
    unsigned r = (u + 0x7fffu + ((u >> 16) & 1u)) >> 16;   // round-nearest-even
    return (unsigned short)r;
}

// ---------------- zero counts ----------------
__global__ void zero_kernel(unsigned* __restrict__ p, int n) {
    int i = blockIdx.x * blockDim.x + threadIdx.x;
    int stride = gridDim.x * blockDim.x;
    for (; i < n; i += stride) p[i] = 0u;
}

// ---------------- count in-degree (edges only; self-loop added analytically) ----------------
__global__ void count_kernel(const int* __restrict__ ei, unsigned* __restrict__ count,
                             int E, int n) {
    int i = blockIdx.x * blockDim.x + threadIdx.x;
    int stride = gridDim.x * blockDim.x;
    for (; i < E; i += stride) {
        int dst = ei[(size_t)E + i];
        if ((unsigned)dst < (unsigned)n) atomicAdd(&count[dst], 1u);
    }
}

// ---------------- single-block exclusive scan + dinv ----------------
__global__ void scan_kernel(const unsigned* __restrict__ count, unsigned* __restrict__ off,
                            unsigned* __restrict__ woff, float* __restrict__ dinv, int n) {
    __shared__ unsigned sums[1024];
    int t = threadIdx.x;
    int chunk = (n + 1023) >> 10;
    int beg = min(t * chunk, n);
    int end = min(beg + chunk, n);
    unsigned local = 0;
    for (int i = beg; i < end; ++i) local += count[i];
    sums[t] = local;
    __syncthreads();
    for (int d = 1; d < 1024; d <<= 1) {
        unsigned v = (t >= d) ? sums[t - d] : 0u;
        __syncthreads();
        sums[t] += v;
        __syncthreads();
    }
    unsigned run = (t > 0) ? sums[t - 1] : 0u;
    for (int i = beg; i < end; ++i) {
        unsigned cnt = count[i];
        off[i] = run;
        woff[i] = run;
        dinv[i] = rsqrtf((float)(cnt + 1u));  // +1 self-loop
        run += cnt;
    }
    if (t == 0) off[n] = sums[1023];
}

// ---------------- scatter src indices grouped by dst ----------------
__global__ void scatter_kernel(const int* __restrict__ ei, unsigned* __restrict__ woff,
                               int* __restrict__ srcs, int E, int n) {
    int i = blockIdx.x * blockDim.x + threadIdx.x;
    int stride = gridDim.x * blockDim.x;
    for (; i < E; i += stride) {
        int s = ei[i];
        int dst = ei[(size_t)E + i];
        if ((unsigned)s >= (unsigned)n || (unsigned)dst >= (unsigned)n) continue;
        unsigned p = atomicAdd(&woff[dst], 1u);
        if (p < (unsigned)E) srcs[p] = s;
    }
}

// ---------------- h = (x + h_cur) @ W[:, 0:128]  (W is 128x512 row-major), bf16 out ----------------
__global__ __launch_bounds__(256) void gemm_kernel(const float* __restrict__ x,
                                                   const float* __restrict__ hc,
                                                   const float* __restrict__ W,
                                                   unsigned short* __restrict__ h, int n) {
    __shared__ float A[64 * 132];  // 64 rows x 128 k, padded stride 132
    int tid = threadIdx.x;
    int r0 = blockIdx.x * 64;

    // stage combined = x + h_cur : 64 rows x 128 = 2048 float4
    for (int i = tid; i < 2048; i += 256) {
        int row = i >> 5;           // 32 float4 per row
        int c4 = (i & 31) * 4;
        int grow = r0 + row;
        float4 v;
        if (grow < n) {
            float4 a = *(const float4*)(x + (size_t)grow * HID + c4);
            float4 bb = *(const float4*)(hc + (size_t)grow * HID + c4);
            v = make_float4(a.x + bb.x, a.y + bb.y, a.z + bb.z, a.w + bb.w);
        } else {
            v = make_float4(0.f, 0.f, 0.f, 0.f);
        }
        *(float4*)(&A[row * 132 + c4]) = v;
    }
    __syncthreads();

    int cg = tid & 31;
    int c4 = cg * 4;
    int rg = tid >> 5;  // 0..7 -> rows rg*8 .. +8
    float acc[8][4];
#pragma unroll
    for (int r = 0; r < 8; ++r) {
        acc[r][0] = 0.f; acc[r][1] = 0.f; acc[r][2] = 0.f; acc[r][3] = 0.f;
    }

#pragma unroll 4
    for (int k = 0; k < 128; ++k) {
        float4 w = *(const float4*)(W + (size_t)k * 512 + c4);
#pragma unroll
        for (int r = 0; r < 8; ++r) {
            float a = A[(rg * 8 + r) * 132 + k];
            acc[r][0] += a * w.x;
            acc[r][1] += a * w.y;
            acc[r][2] += a * w.z;
            acc[r][3] += a * w.w;
        }
    }

#pragma unroll
    for (int r = 0; r < 8; ++r) {
        int grow = r0 + rg * 8 + r;
        if (grow < n) {
            unsigned long long pack =
                (unsigned long long)f2b(acc[r][0]) |
                ((unsigned long long)f2b(acc[r][1]) << 16) |
                ((unsigned long long)f2b(acc[r][2]) << 32) |
                ((unsigned long long)f2b(acc[r][3]) << 48);
            *(unsigned long long*)(h + (size_t)grow * HID + c4) = pack;
        }
    }
}

// ---------------- aggregate: one wave per node, 2 cols per lane ----------------
__global__ __launch_bounds__(256) void agg_kernel(const int* __restrict__ srcs,
                                                  const unsigned* __restrict__ off,
                                                  const float* __restrict__ dinv,
                                                  const unsigned short* __restrict__ h,
                                                  const float* __restrict__ b,
                                                  float* __restrict__ out, int n) {
    int wid = (int)((blockIdx.x * (size_t)blockDim.x + threadIdx.x) >> 6);
    int lane = threadIdx.x & 63;
    if (wid >= n) return;
    int d = wid;
    float di = dinv[d];
    unsigned beg = off[d], end = off[d + 1];
    int c = lane * 2;
    float accx = 0.f, accy = 0.f;
    for (unsigned i = beg; i < end; ++i) {
        int s = srcs[i];
        float w = dinv[s];
        ushort2 hv = *(const ushort2*)(h + (size_t)s * HID + c);
        accx += w * b2f(hv.x);
        accy += w * b2f(hv.y);
    }
    ushort2 hd = *(const ushort2*)(h + (size_t)d * HID + c);
    float2 res;
    res.x = di * accx + di * di * b2f(hd.x) + b[c];
    res.y = di * accy + di * di * b2f(hd.y) + b[c + 1];
    *(float2*)(out + (size_t)d * HID + c) = res;
}

extern "C" void kernel_launch(void* const* d_in, const int* in_sizes, int n_in,
                              void* d_out, int out_size, void* d_ws, size_t ws_size,
                              hipStream_t stream) {
    const float* x = (const float*)d_in[0];
    const int* ei = (const int*)d_in[1];       // harness passes integer inputs as int32
    const float* hc = (const float*)d_in[2];
    // d_in[3] = c_cur unused
    const float* W = (const float*)d_in[4];
    const float* b = (const float*)d_in[5];
    float* out = (float*)d_out;

    int n = in_sizes[0] / HID;      // 100000
    int E = in_sizes[1] / 2;        // 3200000

    // workspace layout (16B-aligned offsets), total ~40.0 MB
    char* ws = (char*)d_ws;
    unsigned* count = (unsigned*)(ws);                       // n*4        = 400000
    unsigned* off   = (unsigned*)(ws + 400000);              // (n+1)*4
    unsigned* woff  = (unsigned*)(ws + 800016);              // n*4
    float*    dinv  = (float*)   (ws + 1200016);             // n*4
    int*      srcs  = (int*)     (ws + 1600016);             // E*4        = 12800000
    unsigned short* h = (unsigned short*)(ws + 14400016);    // n*128*2    = 25600000

    zero_kernel<<<512, 256, 0, stream>>>(count, n);
    count_kernel<<<2048, 256, 0, stream>>>(ei, count, E, n);
    scan_kernel<<<1, 1024, 0, stream>>>(count, off, woff, dinv, n);
    scatter_kernel<<<2048, 256, 0, stream>>>(ei, woff, srcs, E, n);

    int gemm_blocks = (n + 63) / 64;
    gemm_kernel<<<gemm_blocks, 256, 0, stream>>>(x, hc, W, h, n);

    int agg_blocks = (n + 3) / 4;   // 4 waves (nodes) per 256-thread block
    agg_kernel<<<agg_blocks, 256, 0, stream>>>(srcs, off, dinv, h, b, out, n);
}

// Round 4
// 664.218 us; speedup vs baseline: 1.5877x; 1.5877x over previous
//
#include <hip/hip_runtime.h>
#include <hip/hip_bf16.h>

#define HID 128

__device__ __forceinline__ float b2f(unsigned short u) {
    union { unsigned i; float f; } v; v.i = ((unsigned)u) << 16; return v.f;
}
__device__ __forceinline__ unsigned short f2b(float f) {
    unsigned u = __float_as_uint(f);
    unsigned r = (u + 0x7fffu + ((u >> 16) & 1u)) >> 16;   // round-nearest-even
    return (unsigned short)r;
}

// ---------------- zero counts ----------------
__global__ void zero_kernel(unsigned* __restrict__ p, int n) {
    int i = blockIdx.x * blockDim.x + threadIdx.x;
    int stride = gridDim.x * blockDim.x;
    for (; i < n; i += stride) p[i] = 0u;
}

// ---------------- count in-degree (edges only; self-loop added analytically) ----------------
__global__ void count_kernel(const int* __restrict__ ei, unsigned* __restrict__ count,
                             int E, int n) {
    int i = blockIdx.x * blockDim.x + threadIdx.x;
    int stride = gridDim.x * blockDim.x;
    for (; i < E; i += stride) {
        int dst = ei[(size_t)E + i];
        if ((unsigned)dst < (unsigned)n) atomicAdd(&count[dst], 1u);
    }
}

// ---------------- multi-block scan, stage 1: per-block sums ----------------
__global__ __launch_bounds__(256) void scan1_kernel(const unsigned* __restrict__ count,
                                                    unsigned* __restrict__ partial, int n) {
    __shared__ unsigned sdata[256];
    int t = threadIdx.x;
    int idx = blockIdx.x * 256 + t;
    unsigned v = (idx < n) ? count[idx] : 0u;
    sdata[t] = v;
    __syncthreads();
    for (int d = 128; d > 0; d >>= 1) {
        if (t < d) sdata[t] += sdata[t + d];
        __syncthreads();
    }
    if (t == 0) partial[blockIdx.x] = sdata[0];
}

// ---------------- stage 2: scan of block partials (nb <= 512) ----------------
__global__ __launch_bounds__(512) void scan2_kernel(const unsigned* __restrict__ partial,
                                                    unsigned* __restrict__ blockpre,
                                                    unsigned* __restrict__ off,
                                                    int nb, int n) {
    __shared__ unsigned sdata[512];
    int t = threadIdx.x;
    unsigned v = (t < nb) ? partial[t] : 0u;
    sdata[t] = v;
    __syncthreads();
    for (int d = 1; d < 512; d <<= 1) {
        unsigned add = (t >= d) ? sdata[t - d] : 0u;
        __syncthreads();
        sdata[t] += add;
        __syncthreads();
    }
    if (t < nb) blockpre[t] = sdata[t] - v;   // exclusive
    if (t == 511) off[n] = sdata[511];        // grand total
}

// ---------------- stage 3: per-block exclusive scan + apply + dinv ----------------
__global__ __launch_bounds__(256) void scan3_kernel(const unsigned* __restrict__ count,
                                                    const unsigned* __restrict__ blockpre,
                                                    unsigned* __restrict__ off,
                                                    unsigned* __restrict__ woff,
                                                    float* __restrict__ dinv, int n) {
    __shared__ unsigned sdata[256];
    int t = threadIdx.x;
    int idx = blockIdx.x * 256 + t;
    unsigned v = (idx < n) ? count[idx] : 0u;
    sdata[t] = v;
    __syncthreads();
    for (int d = 1; d < 256; d <<= 1) {
        unsigned add = (t >= d) ? sdata[t - d] : 0u;
        __syncthreads();
        sdata[t] += add;
        __syncthreads();
    }
    if (idx < n) {
        unsigned excl = sdata[t] - v + blockpre[blockIdx.x];
        off[idx] = excl;
        woff[idx] = excl;
        dinv[idx] = rsqrtf((float)(v + 1u));  // +1 self-loop
    }
}

// ---------------- scatter src indices grouped by dst ----------------
__global__ void scatter_kernel(const int* __restrict__ ei, unsigned* __restrict__ woff,
                               int* __restrict__ srcs, int E, int n) {
    int i = blockIdx.x * blockDim.x + threadIdx.x;
    int stride = gridDim.x * blockDim.x;
    for (; i < E; i += stride) {
        int s = ei[i];
        int dst = ei[(size_t)E + i];
        if ((unsigned)s >= (unsigned)n || (unsigned)dst >= (unsigned)n) continue;
        unsigned p = atomicAdd(&woff[dst], 1u);
        if (p < (unsigned)E) srcs[p] = s;
    }
}

// ---------------- h = (x + h_cur) @ W[:, 0:128]  (W is 128x512 row-major), bf16 out ----------------
__global__ __launch_bounds__(256) void gemm_kernel(const float* __restrict__ x,
                                                   const float* __restrict__ hc,
                                                   const float* __restrict__ W,
                                                   unsigned short* __restrict__ h, int n) {
    __shared__ float A[64 * 132];  // 64 rows x 128 k, padded stride 132
    int tid = threadIdx.x;
    int r0 = blockIdx.x * 64;

    for (int i = tid; i < 2048; i += 256) {
        int row = i >> 5;
        int c4 = (i & 31) * 4;
        int grow = r0 + row;
        float4 v;
        if (grow < n) {
            float4 a = *(const float4*)(x + (size_t)grow * HID + c4);
            float4 bb = *(const float4*)(hc + (size_t)grow * HID + c4);
            v = make_float4(a.x + bb.x, a.y + bb.y, a.z + bb.z, a.w + bb.w);
        } else {
            v = make_float4(0.f, 0.f, 0.f, 0.f);
        }
        *(float4*)(&A[row * 132 + c4]) = v;
    }
    __syncthreads();

    int cg = tid & 31;
    int c4 = cg * 4;
    int rg = tid >> 5;
    float acc[8][4];
#pragma unroll
    for (int r = 0; r < 8; ++r) {
        acc[r][0] = 0.f; acc[r][1] = 0.f; acc[r][2] = 0.f; acc[r][3] = 0.f;
    }

#pragma unroll 4
    for (int k = 0; k < 128; ++k) {
        float4 w = *(const float4*)(W + (size_t)k * 512 + c4);
#pragma unroll
        for (int r = 0; r < 8; ++r) {
            float a = A[(rg * 8 + r) * 132 + k];
            acc[r][0] += a * w.x;
            acc[r][1] += a * w.y;
            acc[r][2] += a * w.z;
            acc[r][3] += a * w.w;
        }
    }

#pragma unroll
    for (int r = 0; r < 8; ++r) {
        int grow = r0 + rg * 8 + r;
        if (grow < n) {
            unsigned long long pack =
                (unsigned long long)f2b(acc[r][0]) |
                ((unsigned long long)f2b(acc[r][1]) << 16) |
                ((unsigned long long)f2b(acc[r][2]) << 32) |
                ((unsigned long long)f2b(acc[r][3]) << 48);
            *(unsigned long long*)(h + (size_t)grow * HID + c4) = pack;
        }
    }
}

// ---------------- aggregate: one wave per node, 2 cols per lane, 4-deep MLP ----------------
__global__ __launch_bounds__(256) void agg_kernel(const int* __restrict__ srcs,
                                                  const unsigned* __restrict__ off,
                                                  const float* __restrict__ dinv,
                                                  const unsigned short* __restrict__ h,
                                                  const float* __restrict__ b,
                                                  float* __restrict__ out, int n) {
    int wid = (int)((blockIdx.x * (size_t)blockDim.x + threadIdx.x) >> 6);
    int lane = threadIdx.x & 63;
    if (wid >= n) return;
    int d = wid;
    float di = dinv[d];
    unsigned beg = off[d], end = off[d + 1];
    int c = lane * 2;
    float accx = 0.f, accy = 0.f;

    unsigned i = beg;
    // main: 4 independent rows in flight per wave
    for (; i + 4 <= end; i += 4) {
        int s0 = srcs[i], s1 = srcs[i + 1], s2 = srcs[i + 2], s3 = srcs[i + 3];
        float w0 = dinv[s0], w1 = dinv[s1], w2 = dinv[s2], w3 = dinv[s3];
        ushort2 v0 = *(const ushort2*)(h + (size_t)s0 * HID + c);
        ushort2 v1 = *(const ushort2*)(h + (size_t)s1 * HID + c);
        ushort2 v2 = *(const ushort2*)(h + (size_t)s2 * HID + c);
        ushort2 v3 = *(const ushort2*)(h + (size_t)s3 * HID + c);
        accx += w0 * b2f(v0.x); accy += w0 * b2f(v0.y);
        accx += w1 * b2f(v1.x); accy += w1 * b2f(v1.y);
        accx += w2 * b2f(v2.x); accy += w2 * b2f(v2.y);
        accx += w3 * b2f(v3.x); accy += w3 * b2f(v3.y);
    }
    // branchless clamped tail: still 4 rows in flight, zero-weighted beyond end
    if (i < end) {
        unsigned last = end - 1;
        unsigned j1 = min(i + 1, last), j2 = min(i + 2, last), j3 = min(i + 3, last);
        int s0 = srcs[i], s1 = srcs[j1], s2 = srcs[j2], s3 = srcs[j3];
        float w0 = dinv[s0];
        float w1 = (i + 1 < end) ? dinv[s1] : 0.f;
        float w2 = (i + 2 < end) ? dinv[s2] : 0.f;
        float w3 = (i + 3 < end) ? dinv[s3] : 0.f;
        ushort2 v0 = *(const ushort2*)(h + (size_t)s0 * HID + c);
        ushort2 v1 = *(const ushort2*)(h + (size_t)s1 * HID + c);
        ushort2 v2 = *(const ushort2*)(h + (size_t)s2 * HID + c);
        ushort2 v3 = *(const ushort2*)(h + (size_t)s3 * HID + c);
        accx += w0 * b2f(v0.x); accy += w0 * b2f(v0.y);
        accx += w1 * b2f(v1.x); accy += w1 * b2f(v1.y);
        accx += w2 * b2f(v2.x); accy += w2 * b2f(v2.y);
        accx += w3 * b2f(v3.x); accy += w3 * b2f(v3.y);
    }

    ushort2 hd = *(const ushort2*)(h + (size_t)d * HID + c);
    float2 res;
    res.x = di * accx + di * di * b2f(hd.x) + b[c];
    res.y = di * accy + di * di * b2f(hd.y) + b[c + 1];
    *(float2*)(out + (size_t)d * HID + c) = res;
}

extern "C" void kernel_launch(void* const* d_in, const int* in_sizes, int n_in,
                              void* d_out, int out_size, void* d_ws, size_t ws_size,
                              hipStream_t stream) {
    const float* x = (const float*)d_in[0];
    const int* ei = (const int*)d_in[1];       // harness passes integer inputs as int32
    const float* hc = (const float*)d_in[2];
    // d_in[3] = c_cur unused
    const float* W = (const float*)d_in[4];
    const float* b = (const float*)d_in[5];
    float* out = (float*)d_out;

    int n = in_sizes[0] / HID;      // 100000
    int E = in_sizes[1] / 2;        // 3200000

    // workspace layout (16B-aligned offsets), total ~40.0 MB
    char* ws = (char*)d_ws;
    unsigned* count   = (unsigned*)(ws);                     // n*4
    unsigned* off     = (unsigned*)(ws + 400000);            // (n+1)*4
    unsigned* woff    = (unsigned*)(ws + 800016);            // n*4
    float*    dinv    = (float*)   (ws + 1200016);           // n*4
    int*      srcs    = (int*)     (ws + 1600016);           // E*4 = 12.8MB
    unsigned short* h = (unsigned short*)(ws + 14400016);    // n*128*2 = 25.6MB
    unsigned* partial = (unsigned*)(ws + 40000016);          // 512*4
    unsigned* blockpre= (unsigned*)(ws + 40002064);          // 512*4

    int nb = (n + 255) / 256;   // 391 for n=100000 (fits scan2's 512 slots)

    zero_kernel<<<512, 256, 0, stream>>>(count, n);
    count_kernel<<<2048, 256, 0, stream>>>(ei, count, E, n);
    scan1_kernel<<<nb, 256, 0, stream>>>(count, partial, n);
    scan2_kernel<<<1, 512, 0, stream>>>(partial, blockpre, off, nb, n);
    scan3_kernel<<<nb, 256, 0, stream>>>(count, blockpre, off, woff, dinv, n);
    scatter_kernel<<<2048, 256, 0, stream>>>(ei, woff, srcs, E, n);

    int gemm_blocks = (n + 63) / 64;
    gemm_kernel<<<gemm_blocks, 256, 0, stream>>>(x, hc, W, h, n);

    int agg_blocks = (n + 3) / 4;   // 4 waves (nodes) per 256-thread block
    agg_kernel<<<agg_blocks, 256, 0, stream>>>(srcs, off, dinv, h, b, out, n);
}

// Round 5
// 319.264 us; speedup vs baseline: 3.3031x; 2.0805x over previous
//
#include <hip/hip_runtime.h>
#include <hip/hip_bf16.h>

#define HID 128
#define BSH 6            // 64 nodes per bucket
#define MAXBUCK 2048     // >= ceil(n/64); n=100000 -> 1563

__device__ __forceinline__ float b2f(unsigned short u) {
    union { unsigned i; float f; } v; v.i = ((unsigned)u) << 16; return v.f;
}
__device__ __forceinline__ unsigned short f2b(float f) {
    unsigned u = __float_as_uint(f);
    return (unsigned short)((u + 0x7fffu + ((u >> 16) & 1u)) >> 16);  // RNE
}

// ---------------- zero bucket counters ----------------
__global__ void zero_kernel(unsigned* __restrict__ p, int n) {
    int i = blockIdx.x * blockDim.x + threadIdx.x;
    if (i < n) p[i] = 0u;
}

// ---------------- K1: bucket histogram (LDS-aggregated) ----------------
__global__ __launch_bounds__(256) void bincount_kernel(const int* __restrict__ ei,
                                                       unsigned* __restrict__ bcount,
                                                       int E, int n, int nbuck) {
    __shared__ unsigned hist[MAXBUCK];
    for (int i = threadIdx.x; i < nbuck; i += 256) hist[i] = 0u;
    __syncthreads();
    int i = blockIdx.x * 256 + threadIdx.x, stride = gridDim.x * 256;
    for (; i < E; i += stride) {
        int dst = ei[(size_t)E + i];
        if ((unsigned)dst < (unsigned)n) atomicAdd(&hist[dst >> BSH], 1u);
    }
    __syncthreads();
    for (int b = threadIdx.x; b < nbuck; b += 256) {
        unsigned c = hist[b];
        if (c) atomicAdd(&bcount[b], c);
    }
}

// ---------------- K2: scan of bucket counts (single block) ----------------
__global__ __launch_bounds__(1024) void bscan_kernel(const unsigned* __restrict__ bcount,
                                                     unsigned* __restrict__ boff,
                                                     unsigned* __restrict__ bwoff,
                                                     unsigned* __restrict__ off,
                                                     int nbuck, int n) {
    __shared__ unsigned sums[1024];
    int t = threadIdx.x;
    int chunk = (nbuck + 1023) >> 10;
    int beg = min(t * chunk, nbuck), end = min(beg + chunk, nbuck);
    unsigned local = 0;
    for (int i = beg; i < end; ++i) local += bcount[i];
    sums[t] = local;
    __syncthreads();
    for (int d = 1; d < 1024; d <<= 1) {
        unsigned v = (t >= d) ? sums[t - d] : 0u;
        __syncthreads();
        sums[t] += v;
        __syncthreads();
    }
    unsigned run = (t > 0) ? sums[t - 1] : 0u;
    for (int i = beg; i < end; ++i) { boff[i] = run; bwoff[i] = run; run += bcount[i]; }
    if (t == 1023) { boff[nbuck] = sums[1023]; off[n] = sums[1023]; }
}

// ---------------- K3: bin-scatter packed edges into bucket runs ----------------
// binned[pos] = (dst&63)<<20 | src   (src < 2^17)
__global__ __launch_bounds__(256) void binscatter_kernel(const int* __restrict__ ei,
                                                         unsigned* __restrict__ bwoff,
                                                         unsigned* __restrict__ binned,
                                                         int E, int n, int nbuck) {
    __shared__ unsigned hist[MAXBUCK];
    __shared__ unsigned base[MAXBUCK];
    int nb = gridDim.x;
    int chunk = (E + nb - 1) / nb;
    int beg = blockIdx.x * chunk, end = min(E, beg + chunk);
    for (int i = threadIdx.x; i < nbuck; i += 256) hist[i] = 0u;
    __syncthreads();
    for (int i = beg + threadIdx.x; i < end; i += 256) {
        int dst = ei[(size_t)E + i];
        if ((unsigned)dst < (unsigned)n) atomicAdd(&hist[dst >> BSH], 1u);
    }
    __syncthreads();
    for (int b = threadIdx.x; b < nbuck; b += 256) {
        unsigned c = hist[b];
        base[b] = c ? atomicAdd(&bwoff[b], c) : 0u;
        hist[b] = 0u;
    }
    __syncthreads();
    for (int i = beg + threadIdx.x; i < end; i += 256) {
        int s = ei[i];
        int dst = ei[(size_t)E + i];
        if ((unsigned)dst >= (unsigned)n) continue;
        unsigned ss = (unsigned)min(max(s, 0), n - 1);
        int b = dst >> BSH;
        unsigned r = atomicAdd(&hist[b], 1u);
        binned[base[b] + r] = ss | ((unsigned)(dst & ((1 << BSH) - 1)) << 20);
    }
}

// ---------------- K4: per-bucket CSR finalize (off, dinv, srcs) ----------------
__global__ __launch_bounds__(256) void csrbuild_kernel(const unsigned* __restrict__ binned,
                                                       const unsigned* __restrict__ boff,
                                                       unsigned* __restrict__ off,
                                                       float* __restrict__ dinv,
                                                       unsigned* __restrict__ srcs,
                                                       int n) {
    __shared__ unsigned hist[64];
    __shared__ unsigned nodeoff[64];
    int b = blockIdx.x;
    unsigned s0 = boff[b], s1 = boff[b + 1];
    int t = threadIdx.x;
    if (t < 64) hist[t] = 0u;
    __syncthreads();
    for (unsigned j = s0 + t; j < s1; j += 256) atomicAdd(&hist[binned[j] >> 20], 1u);
    __syncthreads();
    if (t < 64) {  // wave 0: 64-lane shuffle scan
        unsigned cnt = hist[t];
        unsigned x = cnt;
        for (int d = 1; d < 64; d <<= 1) {
            unsigned v = __shfl_up(x, d, 64);
            if (t >= d) x += v;
        }
        unsigned excl = x - cnt;
        nodeoff[t] = excl;
        hist[t] = 0u;
        int node = (b << BSH) + t;
        if (node < n) {
            off[node] = s0 + excl;
            dinv[node] = rsqrtf((float)(cnt + 1u));  // +1 self-loop
        }
    }
    __syncthreads();
    for (unsigned j = s0 + t; j < s1; j += 256) {
        unsigned p = binned[j];
        unsigned dl = p >> 20, s = p & 0xFFFFFu;
        unsigned r = atomicAdd(&hist[dl], 1u);
        srcs[s0 + nodeoff[dl] + r] = s;
    }
}

// ---------------- h = (x + h_cur) @ W[:, 0:128]  (W is 128x512 row-major), bf16 out ----------------
__global__ __launch_bounds__(256) void gemm_kernel(const float* __restrict__ x,
                                                   const float* __restrict__ hc,
                                                   const float* __restrict__ W,
                                                   unsigned short* __restrict__ h, int n) {
    __shared__ float A[64 * 132];
    int tid = threadIdx.x;
    int r0 = blockIdx.x * 64;

    for (int i = tid; i < 2048; i += 256) {
        int row = i >> 5;
        int c4 = (i & 31) * 4;
        int grow = r0 + row;
        float4 v;
        if (grow < n) {
            float4 a = *(const float4*)(x + (size_t)grow * HID + c4);
            float4 bb = *(const float4*)(hc + (size_t)grow * HID + c4);
            v = make_float4(a.x + bb.x, a.y + bb.y, a.z + bb.z, a.w + bb.w);
        } else {
            v = make_float4(0.f, 0.f, 0.f, 0.f);
        }
        *(float4*)(&A[row * 132 + c4]) = v;
    }
    __syncthreads();

    int cg = tid & 31;
    int c4 = cg * 4;
    int rg = tid >> 5;
    float acc[8][4];
#pragma unroll
    for (int r = 0; r < 8; ++r) {
        acc[r][0] = 0.f; acc[r][1] = 0.f; acc[r][2] = 0.f; acc[r][3] = 0.f;
    }

#pragma unroll 4
    for (int k = 0; k < 128; ++k) {
        float4 w = *(const float4*)(W + (size_t)k * 512 + c4);
#pragma unroll
        for (int r = 0; r < 8; ++r) {
            float a = A[(rg * 8 + r) * 132 + k];
            acc[r][0] += a * w.x;
            acc[r][1] += a * w.y;
            acc[r][2] += a * w.z;
            acc[r][3] += a * w.w;
        }
    }

#pragma unroll
    for (int r = 0; r < 8; ++r) {
        int grow = r0 + rg * 8 + r;
        if (grow < n) {
            unsigned long long pack =
                (unsigned long long)f2b(acc[r][0]) |
                ((unsigned long long)f2b(acc[r][1]) << 16) |
                ((unsigned long long)f2b(acc[r][2]) << 32) |
                ((unsigned long long)f2b(acc[r][3]) << 48);
            *(unsigned long long*)(h + (size_t)grow * HID + c4) = pack;
        }
    }
}

// ---------------- aggregate: one wave per node, 2 cols per lane, 8-deep MLP ----------------
__global__ __launch_bounds__(256) void agg_kernel(const unsigned* __restrict__ srcs,
                                                  const unsigned* __restrict__ off,
                                                  const float* __restrict__ dinv,
                                                  const unsigned short* __restrict__ h,
                                                  const float* __restrict__ b,
                                                  float* __restrict__ out, int n) {
    int wid = (int)((blockIdx.x * (size_t)blockDim.x + threadIdx.x) >> 6);
    int lane = threadIdx.x & 63;
    if (wid >= n) return;
    int d = wid;
    float di = dinv[d];
    unsigned beg = off[d], end = off[d + 1];
    int c = lane * 2;
    float accx = 0.f, accy = 0.f;

    unsigned i = beg;
    for (; i + 8 <= end; i += 8) {
        unsigned s[8]; float w[8]; ushort2 v[8];
#pragma unroll
        for (int k = 0; k < 8; ++k) s[k] = srcs[i + k];
#pragma unroll
        for (int k = 0; k < 8; ++k) w[k] = dinv[s[k]];
#pragma unroll
        for (int k = 0; k < 8; ++k) v[k] = *(const ushort2*)(h + (size_t)s[k] * HID + c);
#pragma unroll
        for (int k = 0; k < 8; ++k) { accx += w[k] * b2f(v[k].x); accy += w[k] * b2f(v[k].y); }
    }
    if (i < end) {
        unsigned last = end - 1;
        unsigned s[8]; float w[8]; ushort2 v[8];
#pragma unroll
        for (int k = 0; k < 8; ++k) {
            unsigned j = min(i + k, last);
            s[k] = srcs[j];
        }
#pragma unroll
        for (int k = 0; k < 8; ++k) w[k] = (i + k < end) ? dinv[s[k]] : 0.f;
#pragma unroll
        for (int k = 0; k < 8; ++k) v[k] = *(const ushort2*)(h + (size_t)s[k] * HID + c);
#pragma unroll
        for (int k = 0; k < 8; ++k) { accx += w[k] * b2f(v[k].x); accy += w[k] * b2f(v[k].y); }
    }

    ushort2 hd = *(const ushort2*)(h + (size_t)d * HID + c);
    float2 res;
    res.x = di * accx + di * di * b2f(hd.x) + b[c];
    res.y = di * accy + di * di * b2f(hd.y) + b[c + 1];
    *(float2*)(out + (size_t)d * HID + c) = res;
}

extern "C" void kernel_launch(void* const* d_in, const int* in_sizes, int n_in,
                              void* d_out, int out_size, void* d_ws, size_t ws_size,
                              hipStream_t stream) {
    const float* x = (const float*)d_in[0];
    const int* ei = (const int*)d_in[1];       // int32 per harness contract
    const float* hc = (const float*)d_in[2];
    // d_in[3] = c_cur unused
    const float* W = (const float*)d_in[4];
    const float* b = (const float*)d_in[5];
    float* out = (float*)d_out;

    int n = in_sizes[0] / HID;      // 100000
    int E = in_sizes[1] / 2;        // 3200000
    int nbuck = (n + 63) >> BSH;    // 1563 (<= MAXBUCK)

    // workspace layout (16B-aligned), total ~39.2 MB
    char* ws = (char*)d_ws;
    unsigned* bcount = (unsigned*)(ws);                  // 8KB region
    unsigned* boff   = (unsigned*)(ws + 8192);           // 8KB region (nbuck+1)
    unsigned* bwoff  = (unsigned*)(ws + 16384);          // 8KB region
    unsigned* off    = (unsigned*)(ws + 24576);          // (n+1)*4
    float*    dinv   = (float*)   (ws + 424592);         // n*4
    unsigned* srcs   = (unsigned*)(ws + 824592);         // E*4 = 12.8MB
    unsigned short* h = (unsigned short*)(ws + 13624592);// n*128*2 = 25.6MB

    // d_out doubles as scratch for the packed binned edges (12.8MB << 51.2MB);
    // agg_kernel fully overwrites d_out afterwards.
    unsigned* binned = (unsigned*)d_out;

    zero_kernel<<<(nbuck + 255) / 256, 256, 0, stream>>>(bcount, nbuck);
    bincount_kernel<<<512, 256, 0, stream>>>(ei, bcount, E, n, nbuck);
    bscan_kernel<<<1, 1024, 0, stream>>>(bcount, boff, bwoff, off, nbuck, n);
    binscatter_kernel<<<256, 256, 0, stream>>>(ei, bwoff, binned, E, n, nbuck);
    csrbuild_kernel<<<nbuck, 256, 0, stream>>>(binned, boff, off, dinv, srcs, n);

    int gemm_blocks = (n + 63) / 64;
    gemm_kernel<<<gemm_blocks, 256, 0, stream>>>(x, hc, W, h, n);

    int agg_blocks = (n + 3) / 4;   // 4 waves (nodes) per 256-thread block
    agg_kernel<<<agg_blocks, 256, 0, stream>>>(srcs, off, dinv, h, b, out, n);
}